// Round 9
// baseline (171.868 us; speedup 1.0000x reference)
//
#include <hip/hip_runtime.h>
#include <math.h>

#define DIM 8
constexpr int B = 8;
constexpr int S = 1024;

// ---------------------------------------------------------------------------
// Kernel 1: q/k projection + grade-wise normalization.
// One thread per (b,s) token. 8192 threads total.
// ---------------------------------------------------------------------------
__global__ void __launch_bounds__(256) prep_qk_kernel(
    const float* __restrict__ x,       // (B,S,8)
    const float* __restrict__ qw,      // (8,8) row = d, col = i
    const float* __restrict__ qb,      // (1,)
    const float* __restrict__ kw,      // (8,8)
    const float* __restrict__ kb,      // (1,)
    const float* __restrict__ an,      // (3000,4)
    float* __restrict__ qn,            // (B,S,8)
    float* __restrict__ kn)            // (B,S,8)
{
    int idx = blockIdx.x * blockDim.x + threadIdx.x;   // b*S + s
    if (idx >= B * S) return;
    int s = idx & (S - 1);

    const float4* xp = reinterpret_cast<const float4*>(x + (size_t)idx * 8);
    float4 xa = xp[0], xb = xp[1];
    float xv[8] = {xa.x, xa.y, xa.z, xa.w, xb.x, xb.y, xb.z, xb.w};

    float sa[4];
#pragma unroll
    for (int g = 0; g < 4; ++g) {
        float a = an[s * 4 + g];
        sa[g] = 1.0f / (1.0f + expf(-a));
    }

    float qv[8], kv[8];
#pragma unroll
    for (int i = 0; i < 8; ++i) {
        float accq = (i == 0) ? qb[0] : 0.0f;
        float acck = (i == 0) ? kb[0] : 0.0f;
#pragma unroll
        for (int d = 0; d < 8; ++d) {
            accq += xv[d] * qw[d * 8 + i];
            acck += xv[d] * kw[d * 8 + i];
        }
        qv[i] = accq;
        kv[i] = acck;
    }

    {
        float n0 = sqrtf(qv[0] * qv[0]);
        float n1 = sqrtf(qv[1] * qv[1] + qv[2] * qv[2] + qv[3] * qv[3]);
        float n2 = sqrtf(qv[4] * qv[4] + qv[5] * qv[5] + qv[6] * qv[6]);
        float n3 = sqrtf(qv[7] * qv[7]);
        float d0 = sa[0] * (n0 - 1.0f) + 1.0f + 1e-6f;
        float d1 = sa[1] * (n1 - 1.0f) + 1.0f + 1e-6f;
        float d2 = sa[2] * (n2 - 1.0f) + 1.0f + 1e-6f;
        float d3 = sa[3] * (n3 - 1.0f) + 1.0f + 1e-6f;
        qv[0] /= d0;
        qv[1] /= d1; qv[2] /= d1; qv[3] /= d1;
        qv[4] /= d2; qv[5] /= d2; qv[6] /= d2;
        qv[7] /= d3;
    }
    {
        float n0 = sqrtf(kv[0] * kv[0]);
        float n1 = sqrtf(kv[1] * kv[1] + kv[2] * kv[2] + kv[3] * kv[3]);
        float n2 = sqrtf(kv[4] * kv[4] + kv[5] * kv[5] + kv[6] * kv[6]);
        float n3 = sqrtf(kv[7] * kv[7]);
        float d0 = sa[0] * (n0 - 1.0f) + 1.0f + 1e-6f;
        float d1 = sa[1] * (n1 - 1.0f) + 1.0f + 1e-6f;
        float d2 = sa[2] * (n2 - 1.0f) + 1.0f + 1e-6f;
        float d3 = sa[3] * (n3 - 1.0f) + 1.0f + 1e-6f;
        kv[0] /= d0;
        kv[1] /= d1; kv[2] /= d1; kv[3] /= d1;
        kv[4] /= d2; kv[5] /= d2; kv[6] /= d2;
        kv[7] /= d3;
    }

    float4* qp = reinterpret_cast<float4*>(qn + (size_t)idx * 8);
    qp[0] = make_float4(qv[0], qv[1], qv[2], qv[3]);
    qp[1] = make_float4(qv[4], qv[5], qv[6], qv[7]);
    float4* kp = reinterpret_cast<float4*>(kn + (size_t)idx * 8);
    kp[0] = make_float4(kv[0], kv[1], kv[2], kv[3]);
    kp[1] = make_float4(kv[4], kv[5], kv[6], kv[7]);
}

// ---------------------------------------------------------------------------
// Kernel 2: pairwise geometric product, ADDRESS-ORDERED grid-stride.
// The output is processed as 131072 contiguous 2KB chunks. Chunk c covers
// row g = c>>4, t in [(c&15)*64, (c&15)*64+64). 2048 waves (512 blocks x 4);
// wave w handles chunks w, w+2048, ... so consecutive waves write consecutive
// 2KB chunks (fillBuffer's address-time pattern: L2 slices / DRAM channels
// round-robin, instantaneous write window ~4MB contiguous). Each wave's
// k-window (c&15 invariant) stays L1-resident across iterations.
// ---------------------------------------------------------------------------
__global__ void __launch_bounds__(256) geomprod_kernel(
    const float* __restrict__ qn,      // (B,S,8)
    const float* __restrict__ kn,      // (B,S,8)
    float* __restrict__ out)           // (B,S,S,8)
{
    const int NW = 2048;                              // total waves
    int wave = blockIdx.x * 4 + (threadIdx.x >> 6);   // 0 .. NW-1
    int lane = threadIdx.x & 63;

#pragma unroll 2
    for (int j = 0; j < 64; ++j) {
        int c = wave + j * NW;          // chunk id, 0 .. 131071
        int g = c >> 4;                 // output row = b*S + s
        int t = (c & 15) * 64 + lane;
        int b = g >> 10;

        const float4* qp = reinterpret_cast<const float4*>(qn + (size_t)g * 8);
        float4 qa = qp[0], qb4 = qp[1];
        float q0 = qa.x, q1 = qa.y, q2 = qa.z, q3 = qa.w;
        float q4 = qb4.x, q5 = qb4.y, q6 = qb4.z, q7 = qb4.w;

        const float4* kp = reinterpret_cast<const float4*>(kn + ((size_t)b * S + t) * 8);
        float4 ka = kp[0], kb4 = kp[1];
        float k0 = ka.x, k1 = ka.y, k2 = ka.z, k3 = ka.w;
        float k4 = kb4.x, k5 = kb4.y, k6 = kb4.z, k7 = kb4.w;

        float o0 = q0*k0 + q1*k1 + q2*k2 + q3*k3 - q4*k4 - q5*k5 - q6*k6 - q7*k7;
        float o1 = q0*k1 + q1*k0 - q2*k4 - q3*k5 + q4*k2 + q5*k3 - q6*k7 - q7*k6;
        float o2 = q0*k2 + q1*k4 + q2*k0 - q3*k6 - q4*k1 + q5*k7 + q6*k3 + q7*k5;
        float o3 = q0*k3 + q1*k5 + q2*k6 + q3*k0 - q4*k7 - q5*k1 - q6*k2 - q7*k4;
        float o4 = q0*k4 + q1*k2 - q2*k1 + q3*k7 + q4*k0 - q5*k6 + q6*k5 + q7*k3;
        float o5 = q0*k5 + q1*k3 - q2*k7 - q3*k1 + q4*k6 + q5*k0 - q6*k4 - q7*k2;
        float o6 = q0*k6 + q1*k7 + q2*k3 - q3*k2 - q4*k5 + q5*k4 + q6*k0 + q7*k1;
        float o7 = q0*k7 + q1*k6 - q2*k5 + q3*k4 + q4*k3 - q5*k2 + q6*k1 + q7*k0;

        // out element offset of chunk c, lane l: c*512 + l*8
        float4* op = reinterpret_cast<float4*>(out + ((size_t)c << 9) + lane * 8);
        op[0] = make_float4(o0, o1, o2, o3);
        op[1] = make_float4(o4, o5, o6, o7);
    }
}

extern "C" void kernel_launch(void* const* d_in, const int* in_sizes, int n_in,
                              void* d_out, int out_size, void* d_ws, size_t ws_size,
                              hipStream_t stream) {
    const float* x  = (const float*)d_in[0];
    const float* qw = (const float*)d_in[1];
    const float* qb = (const float*)d_in[2];
    const float* kw = (const float*)d_in[3];
    const float* kb = (const float*)d_in[4];
    const float* an = (const float*)d_in[5];
    float* out = (float*)d_out;

    float* qn = (float*)d_ws;                       // B*S*8 floats = 256 KB
    float* kn = qn + (size_t)B * S * 8;             // next 256 KB

    int prep_threads = B * S;                        // 8192
    prep_qk_kernel<<<(prep_threads + 255) / 256, 256, 0, stream>>>(
        x, qw, qb, kw, kb, an, qn, kn);

    geomprod_kernel<<<512, 256, 0, stream>>>(qn, kn, out);
}

// Round 10
// 54.732 us; speedup vs baseline: 3.1402x; 3.1402x over previous
//
#include <hip/hip_runtime.h>
#include <math.h>

#define DIM 8
constexpr int B = 8;
constexpr int S = 1024;

__device__ __forceinline__ float rl(float x, int lane) {
    return __int_as_float(__builtin_amdgcn_readlane(__float_as_int(x), lane));
}

// ---------------------------------------------------------------------------
// Kernel 1: q/k projection + grade-wise normalization.
// One thread per (b,s) token. 8192 threads total.
// ---------------------------------------------------------------------------
__global__ void __launch_bounds__(256) prep_qk_kernel(
    const float* __restrict__ x,       // (B,S,8)
    const float* __restrict__ qw,      // (8,8) row = d, col = i
    const float* __restrict__ qb,      // (1,)
    const float* __restrict__ kw,      // (8,8)
    const float* __restrict__ kb,      // (1,)
    const float* __restrict__ an,      // (3000,4)
    float* __restrict__ qn,            // (B,S,8)
    float* __restrict__ kn)            // (B,S,8)
{
    int idx = blockIdx.x * blockDim.x + threadIdx.x;   // b*S + s
    if (idx >= B * S) return;
    int s = idx & (S - 1);

    const float4* xp = reinterpret_cast<const float4*>(x + (size_t)idx * 8);
    float4 xa = xp[0], xb = xp[1];
    float xv[8] = {xa.x, xa.y, xa.z, xa.w, xb.x, xb.y, xb.z, xb.w};

    float sa[4];
#pragma unroll
    for (int g = 0; g < 4; ++g) {
        float a = an[s * 4 + g];
        sa[g] = 1.0f / (1.0f + expf(-a));
    }

    float qv[8], kv[8];
#pragma unroll
    for (int i = 0; i < 8; ++i) {
        float accq = (i == 0) ? qb[0] : 0.0f;
        float acck = (i == 0) ? kb[0] : 0.0f;
#pragma unroll
        for (int d = 0; d < 8; ++d) {
            accq += xv[d] * qw[d * 8 + i];
            acck += xv[d] * kw[d * 8 + i];
        }
        qv[i] = accq;
        kv[i] = acck;
    }

    {
        float n0 = sqrtf(qv[0] * qv[0]);
        float n1 = sqrtf(qv[1] * qv[1] + qv[2] * qv[2] + qv[3] * qv[3]);
        float n2 = sqrtf(qv[4] * qv[4] + qv[5] * qv[5] + qv[6] * qv[6]);
        float n3 = sqrtf(qv[7] * qv[7]);
        float d0 = sa[0] * (n0 - 1.0f) + 1.0f + 1e-6f;
        float d1 = sa[1] * (n1 - 1.0f) + 1.0f + 1e-6f;
        float d2 = sa[2] * (n2 - 1.0f) + 1.0f + 1e-6f;
        float d3 = sa[3] * (n3 - 1.0f) + 1.0f + 1e-6f;
        qv[0] /= d0;
        qv[1] /= d1; qv[2] /= d1; qv[3] /= d1;
        qv[4] /= d2; qv[5] /= d2; qv[6] /= d2;
        qv[7] /= d3;
    }
    {
        float n0 = sqrtf(kv[0] * kv[0]);
        float n1 = sqrtf(kv[1] * kv[1] + kv[2] * kv[2] + kv[3] * kv[3]);
        float n2 = sqrtf(kv[4] * kv[4] + kv[5] * kv[5] + kv[6] * kv[6]);
        float n3 = sqrtf(kv[7] * kv[7]);
        float d0 = sa[0] * (n0 - 1.0f) + 1.0f + 1e-6f;
        float d1 = sa[1] * (n1 - 1.0f) + 1.0f + 1e-6f;
        float d2 = sa[2] * (n2 - 1.0f) + 1.0f + 1e-6f;
        float d3 = sa[3] * (n3 - 1.0f) + 1.0f + 1e-6f;
        kv[0] /= d0;
        kv[1] /= d1; kv[2] /= d1; kv[3] /= d1;
        kv[4] /= d2; kv[5] /= d2; kv[6] /= d2;
        kv[7] /= d3;
    }

    float4* qp = reinterpret_cast<float4*>(qn + (size_t)idx * 8);
    qp[0] = make_float4(qv[0], qv[1], qv[2], qv[3]);
    qp[1] = make_float4(qv[4], qv[5], qv[6], qv[7]);
    float4* kp = reinterpret_cast<float4*>(kn + (size_t)idx * 8);
    kp[0] = make_float4(kv[0], kv[1], kv[2], kv[3]);
    kp[1] = make_float4(kv[4], kv[5], kv[6], kv[7]);
}

// ---------------------------------------------------------------------------
// Kernel 2: pairwise geometric product with a LOAD-FREE store phase.
// 1024 waves (256 blocks x 4). Wave wid: b = wid>>7, s0 = (wid&127)*8.
// Prologue: the FULL k[b] row-set (1024 rows) loaded into 128 VGPRs
// (lane holds k[c*64+lane], c = 0..15), and 8 q rows batch-loaded by one
// dwordx4 across 16 lanes. Then 8 rows x 16 chunks of pure VALU + stores:
// q extracted per-row via v_readlane (no memory op), so after the prologue
// the wave issues 256 dwordx4 stores with ZERO vmcnt waits — store stream
// never serializes on load waits (fillBuffer's profile). Per-wave output:
// 256 KB contiguous; consecutive waves cover consecutive regions.
// ---------------------------------------------------------------------------
__global__ void __launch_bounds__(256) geomprod_kernel(
    const float* __restrict__ qn,      // (B,S,8)
    const float* __restrict__ kn,      // (B,S,8)
    float* __restrict__ out)           // (B,S,S,8)
{
    int lane = threadIdx.x & 63;
    int wid  = blockIdx.x * 4 + (threadIdx.x >> 6);   // 0 .. 1023
    int b    = wid >> 7;                               // 0 .. 7
    int s0   = (wid & 127) * 8;                        // 8 rows per wave

    // --- prologue: k[b] full row-set into registers ---
    float4 kA[16], kB[16];
    const float4* kbase = reinterpret_cast<const float4*>(kn + (size_t)b * S * 8);
#pragma unroll
    for (int c = 0; c < 16; ++c) {
        int t = c * 64 + lane;
        kA[c] = kbase[2 * t];
        kB[c] = kbase[2 * t + 1];
    }

    // --- prologue: 8 q rows batched into one dwordx4 across 16 lanes ---
    // lane l (l<16): row s0 + (l>>1), components (l&1)*4 .. +3
    int ll = lane & 15;
    const float4* qsrc = reinterpret_cast<const float4*>(
        qn + ((size_t)b * S + s0 + (ll >> 1)) * 8) + (ll & 1);
    float4 qbt = *qsrc;

    float* obase0 = out + ((size_t)b * S + s0) * S * 8;

#pragma unroll 1
    for (int j = 0; j < 8; ++j) {
        int lj = 2 * j;
        float q0 = rl(qbt.x, lj),     q1 = rl(qbt.y, lj);
        float q2 = rl(qbt.z, lj),     q3 = rl(qbt.w, lj);
        float q4 = rl(qbt.x, lj + 1), q5 = rl(qbt.y, lj + 1);
        float q6 = rl(qbt.z, lj + 1), q7 = rl(qbt.w, lj + 1);

        float* rowbase = obase0 + (size_t)j * S * 8;

#pragma unroll
        for (int c = 0; c < 16; ++c) {
            float k0 = kA[c].x, k1 = kA[c].y, k2 = kA[c].z, k3 = kA[c].w;
            float k4 = kB[c].x, k5 = kB[c].y, k6 = kB[c].z, k7 = kB[c].w;

            float o0 = q0*k0 + q1*k1 + q2*k2 + q3*k3 - q4*k4 - q5*k5 - q6*k6 - q7*k7;
            float o1 = q0*k1 + q1*k0 - q2*k4 - q3*k5 + q4*k2 + q5*k3 - q6*k7 - q7*k6;
            float o2 = q0*k2 + q1*k4 + q2*k0 - q3*k6 - q4*k1 + q5*k7 + q6*k3 + q7*k5;
            float o3 = q0*k3 + q1*k5 + q2*k6 + q3*k0 - q4*k7 - q5*k1 - q6*k2 - q7*k4;
            float o4 = q0*k4 + q1*k2 - q2*k1 + q3*k7 + q4*k0 - q5*k6 + q6*k5 + q7*k3;
            float o5 = q0*k5 + q1*k3 - q2*k7 - q3*k1 + q4*k6 + q5*k0 - q6*k4 - q7*k2;
            float o6 = q0*k6 + q1*k7 + q2*k3 - q3*k2 - q4*k5 + q5*k4 + q6*k0 + q7*k1;
            float o7 = q0*k7 + q1*k6 - q2*k5 + q3*k4 + q4*k3 - q5*k2 + q6*k1 + q7*k0;

            float4* op = reinterpret_cast<float4*>(rowbase + ((size_t)(c * 64 + lane)) * 8);
            op[0] = make_float4(o0, o1, o2, o3);
            op[1] = make_float4(o4, o5, o6, o7);
        }
    }
}

extern "C" void kernel_launch(void* const* d_in, const int* in_sizes, int n_in,
                              void* d_out, int out_size, void* d_ws, size_t ws_size,
                              hipStream_t stream) {
    const float* x  = (const float*)d_in[0];
    const float* qw = (const float*)d_in[1];
    const float* qb = (const float*)d_in[2];
    const float* kw = (const float*)d_in[3];
    const float* kb = (const float*)d_in[4];
    const float* an = (const float*)d_in[5];
    float* out = (float*)d_out;

    float* qn = (float*)d_ws;                       // B*S*8 floats = 256 KB
    float* kn = qn + (size_t)B * S * 8;             // next 256 KB

    int prep_threads = B * S;                        // 8192
    prep_qk_kernel<<<(prep_threads + 255) / 256, 256, 0, stream>>>(
        x, qw, qb, kw, kb, an, qn, kn);

    geomprod_kernel<<<256, 256, 0, stream>>>(qn, kn, out);
}